// Round 13
// baseline (4767.626 us; speedup 1.0000x reference)
//
#include <hip/hip_runtime.h>
#include <math.h>

// ---------------------------------------------------------------------------
// VAE_14482629722138 — round 18: round-16 base (PASSED, 4753us) + LDS-ONLY
// K-loop barriers (ONLY change; r17's inline-asm loads crashed — compiler
// may move asm-output regs before the waitcnt, rule-#18 hazard class).
// Theory unchanged: __syncthreads = s_waitcnt vmcnt(0) lgkmcnt(0) + s_barrier
// -> per-iter barrier drains all prefetch loads -> pipeline depth ~1.
// Fix: raw "s_waitcnt lgkmcnt(0); s_barrier" in gemm64i's K loop. Loads stay
// compiler-managed (HIP atomic/plain) => compiler inserts COUNTED vmcnt
// waits before each dependent ds_write (verified behavior, guide §7) —
// loads stay in flight across barriers. Step barriers keep __syncthreads.
// B=512, T=64, CF=512, ZD=128, TDIM=520.
// ---------------------------------------------------------------------------

#define B 512
#define TT 64
#define CF 512
#define G4 2048
#define ZD 128
#define TDIM 520

typedef unsigned short u16;
typedef unsigned int u32;
typedef unsigned long long u64;
typedef short bf16x8 __attribute__((ext_vector_type(8)));
typedef float f32x4 __attribute__((ext_vector_type(4)));

__device__ __forceinline__ float sigm(float x) { return 1.f / (1.f + expf(-x)); }
__device__ __forceinline__ u16 f2bf(float f) {
    unsigned u = __float_as_uint(f);
    u += 0x7fffu + ((u >> 16) & 1u);
    return (u16)(u >> 16);
}
__device__ __forceinline__ float bf2f(u16 s) { return __uint_as_float(((unsigned)s) << 16); }
__device__ __forceinline__ u32 packbf(float v) {
    u16 hh = f2bf(v);
    u16 hl = f2bf(v - bf2f(hh));
    return (u32)hh | ((u32)hl << 16);
}

// MALL-coherent (agent-scope, relaxed) accessors — bypass non-coherent L2s.
__device__ __forceinline__ void ast32(u32* p, u32 v) {
    __hip_atomic_store(p, v, __ATOMIC_RELAXED, __HIP_MEMORY_SCOPE_AGENT);
}
__device__ __forceinline__ u64 ald64(const u64* p) {
    return __hip_atomic_load(p, __ATOMIC_RELAXED, __HIP_MEMORY_SCOPE_AGENT);
}
__device__ __forceinline__ void astf(float* p, float v) {
    __hip_atomic_store(p, v, __ATOMIC_RELAXED, __HIP_MEMORY_SCOPE_AGENT);
}
__device__ __forceinline__ float aldf(const float* p) {
    return __hip_atomic_load(p, __ATOMIC_RELAXED, __HIP_MEMORY_SCOPE_AGENT);
}

// Unpack 4 u64 (8 interleaved elements) -> hi-u16x8 and lo-u16x8 vectors.
__device__ __forceinline__ void unpk8(u64 a, u64 b, u64 c, u64 d,
                                      uint4& hi, uint4& lo) {
    u32 a0 = (u32)a, a1 = (u32)(a >> 32);
    u32 b0 = (u32)b, b1 = (u32)(b >> 32);
    u32 c0 = (u32)c, c1 = (u32)(c >> 32);
    u32 d0 = (u32)d, d1 = (u32)(d >> 32);
    hi.x = (a0 & 0xffffu) | (a1 << 16);  lo.x = (a0 >> 16) | (a1 & 0xffff0000u);
    hi.y = (b0 & 0xffffu) | (b1 << 16);  lo.y = (b0 >> 16) | (b1 & 0xffff0000u);
    hi.z = (c0 & 0xffffu) | (c1 << 16);  lo.z = (c0 >> 16) | (c1 & 0xffff0000u);
    hi.w = (d0 & 0xffffu) | (d1 << 16);  lo.w = (d0 >> 16) | (d1 & 0xffff0000u);
}

// Fence-free per-group barrier: RELEASE add + RELAXED spin; no cache ops.
// Uses __syncthreads (full drain) — only at step boundaries.
__device__ __forceinline__ void gsync_fast(int* bar, int target) {
    __syncthreads();
    if (threadIdx.x == 0) {
        __hip_atomic_fetch_add(bar, 1, __ATOMIC_RELEASE, __HIP_MEMORY_SCOPE_AGENT);
        while (__hip_atomic_load(bar, __ATOMIC_RELAXED, __HIP_MEMORY_SCOPE_AGENT) < target)
            __builtin_amdgcn_s_sleep(2);
    }
    __syncthreads();
}

// Full barrier (threadfence both sides) — once at dec prologue.
__device__ __forceinline__ void gsync_full(int* bar, int target) {
    __syncthreads();
    if (threadIdx.x == 0) {
        __threadfence();
        __hip_atomic_fetch_add(bar, 1, __ATOMIC_ACQ_REL, __HIP_MEMORY_SCOPE_AGENT);
        while (__hip_atomic_load(bar, __ATOMIC_ACQUIRE, __HIP_MEMORY_SCOPE_AGENT) < target)
            __builtin_amdgcn_s_sleep(2);
        __threadfence();
    }
    __syncthreads();
}

// K-loop barrier: LDS drain ONLY — in-flight global loads are NOT drained.
__device__ __forceinline__ void lds_barrier() {
    asm volatile("s_waitcnt lgkmcnt(0)\n\ts_barrier" ::: "memory");
}

struct __align__(16) GemmShared {
    u16 A[2][2][64][40];   // [dbuf][hi/lo][row][k(+pad)]
    u16 Bw[2][2][64][40];
};

// Prefetch register set — named fields only (compiler-managed loads).
struct Pref { u64 a0, a1, a2, a3; uint4 bh, bl; };

template<int TERMS>
__device__ __forceinline__ void pf_issue(Pref& p, const u64* xp,
        const u16* wph, const u16* wpl, int it) {
    const int k = it << 5;
    const u64* xq = xp + (k >> 1);
    p.a0 = ald64(xq); p.a1 = ald64(xq + 1);
    p.a2 = ald64(xq + 2); p.a3 = ald64(xq + 3);
    p.bh = *(const uint4*)(wph + k);
    if (TERMS == 3) p.bl = *(const uint4*)(wpl + k);
}

template<int TERMS>
__device__ __forceinline__ void pf_write(GemmShared& sh, const Pref& p,
        int nxt, int srr, int skq) {
    uint4 hi, lo; unpk8(p.a0, p.a1, p.a2, p.a3, hi, lo);
    *(uint4*)&sh.A[nxt][0][srr][skq] = hi;
    *(uint4*)&sh.A[nxt][1][srr][skq] = lo;
    *(uint4*)&sh.Bw[nxt][0][srr][skq] = p.bh;
    if (TERMS == 3) *(uint4*)&sh.Bw[nxt][1][srr][skq] = p.bl;
}

template<int TERMS>
__device__ __forceinline__ void pf_comp(GemmShared& sh, int cur,
        int row, int ko, int fr, f32x4 acc[4]) {
    bf16x8 ah = *(const bf16x8*)&sh.A[cur][0][row][ko];
    bf16x8 al = *(const bf16x8*)&sh.A[cur][1][row][ko];
    #pragma unroll
    for (int nt = 0; nt < 4; ++nt) {
        bf16x8 bh = *(const bf16x8*)&sh.Bw[cur][0][(nt << 4) + fr][ko];
        acc[nt] = __builtin_amdgcn_mfma_f32_16x16x32_bf16(ah, bh, acc[nt], 0, 0, 0);
        if (TERMS == 3) {
            bf16x8 bl = *(const bf16x8*)&sh.Bw[cur][1][(nt << 4) + fr][ko];
            acc[nt] = __builtin_amdgcn_mfma_f32_16x16x32_bf16(ah, bl, acc[nt], 0, 0, 0);
        }
        acc[nt] = __builtin_amdgcn_mfma_f32_16x16x32_bf16(al, bh, acc[nt], 0, 0, 0);
    }
}

// ---------------------------------------------------------------------------
// 64x64 MFMA tile, K multiple of 32, producer/consumer waves, LDS-only
// in-loop barriers (global loads stay in flight; compiler inserts counted
// vmcnt waits before the dependent ds_writes).
// Consumers (tid<256): ds_read + MFMA. Producers (tid>=256): write + issue.
// acc[nt][r]: row = ws*16+quad*4+r, col = nt*16+fr (consumer threads).
// ---------------------------------------------------------------------------
template<int TERMS>
__device__ __forceinline__ void gemm64i(
    GemmShared& sh,
    const u32* __restrict__ A32, int lda,
    const u16* __restrict__ Bh, const u16* __restrict__ Bl, int K, int ldb,
    f32x4 acc[4])
{
    const int tid = threadIdx.x;
    const bool cons = tid < 256;
    const int lane = tid & 63, ws = (tid >> 6) & 3;
    const int fr = lane & 15, quad = lane >> 4, ko = quad << 3;
    const int ptid = tid & 255;
    const int srr = ptid >> 2, skq = (ptid & 3) << 3;
    const int row = (ws << 4) + fr;

    const u64* xp = (const u64*)(A32 + srr * lda + skq);   // 8B-aligned
    const u16* wph = Bh + srr * ldb + skq;
    const u16* wpl = (TERMS == 3) ? (Bl + srr * ldb + skq) : (const u16*)0;

    const int niter = K >> 5;
    Pref pA, pB;
    if (!cons) {
        // stage iter 0 directly
        u64 d0 = ald64(xp), d1 = ald64(xp + 1), d2 = ald64(xp + 2), d3 = ald64(xp + 3);
        uint4 hi, lo; unpk8(d0, d1, d2, d3, hi, lo);
        *(uint4*)&sh.A[0][0][srr][skq] = hi;
        *(uint4*)&sh.A[0][1][srr][skq] = lo;
        *(uint4*)&sh.Bw[0][0][srr][skq] = *(const uint4*)(wph);
        if (TERMS == 3) *(uint4*)&sh.Bw[0][1][srr][skq] = *(const uint4*)(wpl);
        if (niter > 1) pf_issue<TERMS>(pA, xp, wph, wpl, 1);
        if (niter > 2) pf_issue<TERMS>(pB, xp, wph, wpl, 2);
    }
    lds_barrier();

    int i = 0;
    for (;;) {
        // even slot: cur = 0, struct A
        if (cons) {
            pf_comp<TERMS>(sh, 0, row, ko, fr, acc);
        } else if (i + 1 < niter) {
            pf_write<TERMS>(sh, pA, 1, srr, skq);
            if (i + 3 < niter) pf_issue<TERMS>(pA, xp, wph, wpl, i + 3);
        }
        lds_barrier();
        if (++i >= niter) break;
        // odd slot: cur = 1, struct B
        if (cons) {
            pf_comp<TERMS>(sh, 1, row, ko, fr, acc);
        } else if (i + 1 < niter) {
            pf_write<TERMS>(sh, pB, 0, srr, skq);
            if (i + 3 < niter) pf_issue<TERMS>(pB, xp, wph, wpl, i + 3);
        }
        lds_barrier();
        if (++i >= niter) break;
    }
}

// One 64-col strip of the ts head (relu per hidden unit -> N-split exact).
// Must be entered by ALL 512 threads of the block; s[] valid on tid<256.
__device__ __forceinline__ void ts_strip(
    GemmShared& sh, const u32* __restrict__ Xt32r,
    const u16* __restrict__ W1h, const float* __restrict__ b1,
    const float* __restrict__ w2, int ncg, float s[4])
{
    const int lane = threadIdx.x & 63;
    const int fr = lane & 15;
    f32x4 ac[4] = {};
    gemm64i<2>(sh, Xt32r, 512, W1h + (size_t)(ncg << 6) * 512, nullptr, 512, 512, ac);
    s[0] = s[1] = s[2] = s[3] = 0.f;
    if (threadIdx.x < 256) {
        #pragma unroll
        for (int nt = 0; nt < 4; ++nt) {
            int j = (ncg << 6) + (nt << 4) + fr;
            float b1v = b1[j], w2v = w2[j];
            s[0] += fmaxf(ac[nt][0] + b1v, 0.f) * w2v;
            s[1] += fmaxf(ac[nt][1] + b1v, 0.f) * w2v;
            s[2] += fmaxf(ac[nt][2] + b1v, 0.f) * w2v;
            s[3] += fmaxf(ac[nt][3] + b1v, 0.f) * w2v;
        }
        #pragma unroll
        for (int off = 1; off < 16; off <<= 1) {
            s[0] += __shfl_xor(s[0], off);
            s[1] += __shfl_xor(s[1], off);
            s[2] += __shfl_xor(s[2], off);
            s[3] += __shfl_xor(s[3], off);
        }
    }
}

// ---------------------------------------------------------------------------
// Persistent encoder: 64 steps, one per-by barrier per step. 512 threads.
// ---------------------------------------------------------------------------
__global__ __launch_bounds__(512, 1) void enc_coop(
    u32* __restrict__ Xe32,                     // 2 x B x 608 interleaved
    const u16* __restrict__ Weh, const u16* __restrict__ Wel,
    const float* __restrict__ biaspk,
    float* __restrict__ tcat, const int* __restrict__ lens,
    const int* __restrict__ acts, const float* __restrict__ tsv,
    const float* __restrict__ act_emb, int* __restrict__ bars)
{
    __shared__ GemmShared sh;
    const int bx = blockIdx.x, by = blockIdx.y, row0 = by << 6;
    const int tid = threadIdx.x;
    const bool cons = tid < 256;
    const int lane = tid & 63, ws = (tid >> 6) & 3;
    const int fr = lane & 15, quad = lane >> 4;
    const int cell = (bx << 4) + fr;
    const int rbase = row0 + (ws << 4) + (quad << 2);
    int* bar = bars + by * 32;
    int gen = 0;

    float bb[4], ce[4] = {0.f, 0.f, 0.f, 0.f};
    int lm1[4];
    #pragma unroll
    for (int g = 0; g < 4; ++g) bb[g] = biaspk[(bx << 6) + (g << 4) + fr];
    #pragma unroll
    for (int r = 0; r < 4; ++r) lm1[r] = lens[rbase + r] - 1;

    for (int t = 0; t < TT; ++t) {
        const u32* xc = Xe32 + (size_t)(t & 1) * B * 608;
        u32* xn = Xe32 + (size_t)((t + 1) & 1) * B * 608;

        f32x4 acc[4] = {};
        gemm64i<3>(sh, xc + (size_t)row0 * 608, 608,
                   Weh + (size_t)(bx << 6) * 608, Wel + (size_t)(bx << 6) * 608,
                   608, 608, acc);

        if (cons) {
            #pragma unroll
            for (int r = 0; r < 4; ++r) {
                int b = rbase + r;
                float gi = acc[0][r] + bb[0], gf = acc[1][r] + bb[1];
                float gg = acc[2][r] + bb[2], go = acc[3][r] + bb[3];
                float cn = sigm(gf) * ce[r] + sigm(gi) * tanhf(gg);
                ce[r] = cn;
                float h = sigm(go) * tanhf(cn);
                ast32(&xn[b * 608 + 65 + cell], packbf(h));
                if (t == lm1[r]) tcat[b * TDIM + 8 + cell] = h;
            }
        }
        if (t < TT - 1) {
            // next-x staging: each (bx,by) covers 2 rows x 65 cols
            for (int idx = tid; idx < 130; idx += 512) {
                int hi2 = (idx >= 65);
                int r = (bx << 1) + hi2, cc = idx - hi2 * 65;
                int b = row0 + r;
                float v = (cc < 64) ? act_emb[acts[(b << 6) + t + 1] * 64 + cc]
                                    : tsv[(b << 6) + t + 1];
                ast32(&xn[b * 608 + cc], packbf(v));
            }
            gsync_fast(bar, (++gen) * 32);
        }
    }
}

// ---------------------------------------------------------------------------
// Persistent decoder: Wa pack (global full barrier once), then 64 steps with
// 2 per-by barriers each, then ts tail. 512 threads, producer/consumer.
// ---------------------------------------------------------------------------
__global__ __launch_bounds__(512, 1) void dec_coop(
    u32* __restrict__ Xa32,                     // 2 x B x 576 interleaved
    u16* Wah, u16* Wal,
    const float* __restrict__ aWih, const float* __restrict__ aWhh,
    const float* __restrict__ base_a,
    u32* __restrict__ Xt32,                     // 2 x B x 512 interleaved
    const u16* __restrict__ Wth, const u16* __restrict__ Wtl,
    const float* __restrict__ base_t,
    const u16* __restrict__ E2h, const u16* __restrict__ E2l,
    const float* __restrict__ e2b, const float* __restrict__ act_emb,
    float* __restrict__ out_acts, float* __restrict__ out_ts,
    const u16* __restrict__ W1h, const float* __restrict__ b1,
    const float* __restrict__ w2, const float* __restrict__ b2p,
    float* __restrict__ tspart, int* __restrict__ bars)
{
    __shared__ GemmShared sh;
    __shared__ u16 ae2h[64][72];
    __shared__ u16 ae2l[64][72];
    const int bx = blockIdx.x, by = blockIdx.y, row0 = by << 6;
    const int tid = threadIdx.x;
    const bool cons = tid < 256;
    const int lane = tid & 63, ws = (tid >> 6) & 3;
    const int fr = lane & 15, quad = lane >> 4;
    const int ptid = tid & 255;
    const int srr = ptid >> 2, skq = (ptid & 3) << 3;
    const bool bx0 = (bx == 0);
    const int cell = (bx << 4) + fr;
    const int rb0 = (ws << 4) + (quad << 2);
    const int rbase = row0 + rb0;
    const float tsb2 = b2p[0];
    int* barG = bars + 512;            // global (256 contenders), used once
    int* bar  = bars + 256 + by * 32;  // per-by (32 contenders)
    int gen = 0;

    // ---- prologue: pack Wa (plain stores; full fence publishes) ----
    {
        const int gtid = (((by << 5) + bx) << 9) + tid;
        for (int idx = gtid; idx < G4 * 576; idx += 32 * 8 * 512) {
            int np = idx / 576, k = idx - np * 576;
            int g = (np & 63) >> 4;
            int n = (g << 9) + (((np >> 6) << 4) + (np & 15));
            float v = (k < 64) ? aWih[n * 584 + 520 + k] : aWhh[(n << 9) + k - 64];
            u16 h = f2bf(v);
            Wah[idx] = h; Wal[idx] = f2bf(v - bf2f(h));
        }
    }

    float e2bv[4];
    float ca_r[4] = {0.f, 0.f, 0.f, 0.f}, ct_r[4] = {0.f, 0.f, 0.f, 0.f};
    #pragma unroll
    for (int nt = 0; nt < 4; ++nt) e2bv[nt] = e2b[(nt << 4) + fr];

    gsync_full(barG, 256);   // Wa visible; stale L2 lines evicted

    for (int t = 0; t < TT; ++t) {
        u32* xac = Xa32 + (size_t)(t & 1) * B * 576;
        u32* xan = Xa32 + (size_t)((t + 1) & 1) * B * 576;
        const u32* xtc = Xt32 + (size_t)(t & 1) * B * 512;
        u32* xtn = Xt32 + (size_t)((t + 1) & 1) * B * 512;

        // ============ phase 1: gemm_a + cell_a (+ ts strip on bx<4) ======
        {
            f32x4 acc[4] = {};
            gemm64i<3>(sh, xac + (size_t)row0 * 576, 576,
                       Wah + (size_t)(bx << 6) * 576, Wal + (size_t)(bx << 6) * 576,
                       576, 576, acc);
            if (cons) {
                #pragma unroll
                for (int r = 0; r < 4; ++r) {
                    int b = rbase + r;
                    const float* bp = base_a + (size_t)b * G4 + (bx << 6) + fr;
                    float gi = acc[0][r] + bp[0], gf = acc[1][r] + bp[16];
                    float gg = acc[2][r] + bp[32], go = acc[3][r] + bp[48];
                    float cn = sigm(gf) * ca_r[r] + sigm(gi) * tanhf(gg);
                    ca_r[r] = cn;
                    float h = sigm(go) * tanhf(cn);
                    ast32(&xan[b * 576 + 64 + cell], packbf(h));
                }
            }
            if (bx < 4 && t > 0) {
                float s[4];
                ts_strip(sh, xtc + (size_t)row0 * 512, W1h, b1, w2, bx, s);
                if (cons && fr == 0) {
                    #pragma unroll
                    for (int r = 0; r < 4; ++r) astf(&tspart[(bx << 9) + rbase + r], s[r]);
                }
            }
        }
        gsync_fast(bar, (++gen) * 32);

        // ============ phase 2: act head + gemm_t + cell_t ================
        if (t > 0 && bx == 1 && tid < 64) {
            int b = row0 + tid;
            out_ts[(b << 6) + t - 1] =
                aldf(&tspart[b]) + aldf(&tspart[512 + b]) +
                aldf(&tspart[1024 + b]) + aldf(&tspart[1536 + b]) + tsb2;
        }
        // tsc for this thread's staging row (producers use it in the tail)
        float tsq = 0.f;
        if (t > 0) {
            int b = row0 + srr;
            tsq = aldf(&tspart[b]) + aldf(&tspart[512 + b]) +
                  aldf(&tspart[1024 + b]) + aldf(&tspart[1536 + b]) + tsb2;
        }
        {   // act head (block-local; reads h_a region of xan)
            f32x4 acc[4] = {};
            gemm64i<3>(sh, xan + (size_t)row0 * 576 + 64, 576, E2h, E2l, 512, 512, acc);
            if (cons) {
                #pragma unroll
                for (int r = 0; r < 4; ++r) {
                    float l0 = acc[0][r] + e2bv[0], l1 = acc[1][r] + e2bv[1];
                    float l2 = acc[2][r] + e2bv[2], l3 = acc[3][r] + e2bv[3];
                    float m = fmaxf(fmaxf(l0, l1), fmaxf(l2, l3));
                    #pragma unroll
                    for (int off = 1; off < 16; off <<= 1) m = fmaxf(m, __shfl_xor(m, off));
                    float e0 = expf(l0 - m), e1 = expf(l1 - m);
                    float e2v = expf(l2 - m), e3 = expf(l3 - m);
                    float sm = e0 + e1 + e2v + e3;
                    #pragma unroll
                    for (int off = 1; off < 16; off <<= 1) sm += __shfl_xor(sm, off);
                    float bv = l0; int bc = fr;
                    if (l1 > bv) { bv = l1; bc = 16 + fr; }
                    if (l2 > bv) { bv = l2; bc = 32 + fr; }
                    if (l3 > bv) { bv = l3; bc = 48 + fr; }
                    #pragma unroll
                    for (int off = 1; off < 16; off <<= 1) {
                        float ov = __shfl_xor(bv, off);
                        int oc = __shfl_xor(bc, off);
                        if (ov > bv || (ov == bv && oc < bc)) { bv = ov; bc = oc; }
                    }
                    int rl = rb0 + r, b = row0 + rl;
                    if (bx0) {
                        float inv = 1.f / sm;
                        float* op = out_acts + (((size_t)(b << 6) + t) << 6);
                        op[fr] = e0 * inv; op[16 + fr] = e1 * inv;
                        op[32 + fr] = e2v * inv; op[48 + fr] = e3 * inv;
                    }
                    #pragma unroll
                    for (int ci = 0; ci < 4; ++ci) {
                        int cc = (fr << 2) + ci;
                        float v = act_emb[(bc << 6) + cc];
                        u16 hh = f2bf(v), hl = f2bf(v - bf2f(hh));
                        ae2h[rl][cc] = hh; ae2l[rl][cc] = hl;
                        if (bx0) ast32(&xan[b * 576 + cc], ((u32)hh) | ((u32)hl << 16));
                    }
                }
            }
        }
        __syncthreads();   // ae2 visible to producers for the tail

        // gemm_t: pipelined K=512 part (A = Xt), then 3 on-chip tail iters
        f32x4 acc[4] = {};
        gemm64i<3>(sh, xtc + (size_t)row0 * 512, 512,
                   Wth + (size_t)(bx << 6) * 608, Wtl + (size_t)(bx << 6) * 608,
                   512, 608, acc);
        {
            const u16* wph = Wth + (size_t)((bx << 6) + srr) * 608 + skq;
            const u16* wpl = Wtl + (size_t)((bx << 6) + srr) * 608 + skq;
            const int ko = quad << 3;
            for (int it = 16; it < 19; ++it) {
                int k0 = it << 5;
                uint4 vh, vl, wh, wl;
                if (!cons) {
                    if (it < 18) {
                        int co = k0 - 512 + skq;
                        vh = *(const uint4*)&ae2h[srr][co];
                        vl = *(const uint4*)&ae2l[srr][co];
                    } else {
                        union U { uint4 q; u16 s[8]; } uh, ul;
                        uh.q = make_uint4(0, 0, 0, 0); ul.q = make_uint4(0, 0, 0, 0);
                        if (skq == 0) {
                            u16 hh = f2bf(tsq);
                            uh.s[0] = hh; ul.s[0] = f2bf(tsq - bf2f(hh));
                        }
                        vh = uh.q; vl = ul.q;
                    }
                    wh = *(const uint4*)(wph + k0);
                    wl = *(const uint4*)(wpl + k0);
                }
                __syncthreads();   // prior MFMA reads of sh complete
                if (!cons) {
                    *(uint4*)&sh.A[0][0][srr][skq] = vh;
                    *(uint4*)&sh.A[0][1][srr][skq] = vl;
                    *(uint4*)&sh.Bw[0][0][srr][skq] = wh;
                    *(uint4*)&sh.Bw[0][1][srr][skq] = wl;
                }
                __syncthreads();
                if (cons) {
                    bf16x8 ah = *(const bf16x8*)&sh.A[0][0][(ws << 4) + fr][ko];
                    bf16x8 al = *(const bf16x8*)&sh.A[0][1][(ws << 4) + fr][ko];
                    #pragma unroll
                    for (int nt = 0; nt < 4; ++nt) {
                        bf16x8 bh = *(const bf16x8*)&sh.Bw[0][0][(nt << 4) + fr][ko];
                        bf16x8 bl = *(const bf16x8*)&sh.Bw[0][1][(nt << 4) + fr][ko];
                        acc[nt] = __builtin_amdgcn_mfma_f32_16x16x32_bf16(ah, bh, acc[nt], 0, 0, 0);
                        acc[nt] = __builtin_amdgcn_mfma_f32_16x16x32_bf16(ah, bl, acc[nt], 0, 0, 0);
                        acc[nt] = __builtin_amdgcn_mfma_f32_16x16x32_bf16(al, bh, acc[nt], 0, 0, 0);
                    }
                }
            }
        }
        // cell_t
        if (cons) {
            #pragma unroll
            for (int r = 0; r < 4; ++r) {
                int b = rbase + r;
                const float* bp = base_t + (size_t)b * G4 + (bx << 6) + fr;
                float gi = acc[0][r] + bp[0], gf = acc[1][r] + bp[16];
                float gg = acc[2][r] + bp[32], go = acc[3][r] + bp[48];
                float cn = sigm(gf) * ct_r[r] + sigm(gi) * tanhf(gg);
                ct_r[r] = cn;
                float h = sigm(go) * tanhf(cn);
                ast32(&xtn[(b << 9) + cell], packbf(h));
            }
        }
        gsync_fast(bar, (++gen) * 32);
    }

    // ---- tail: ts head on final h_t (buffer 0, TT even) ----
    if (bx < 4) {
        float s[4];
        ts_strip(sh, Xt32 + (size_t)row0 * 512, W1h, b1, w2, bx, s);
        if (cons && fr == 0) {
            #pragma unroll
            for (int r = 0; r < 4; ++r) astf(&tspart[(bx << 9) + rbase + r], s[r]);
        }
    }
    gsync_fast(bar, (++gen) * 32);
    if (bx == 0 && tid < 64) {
        int b = row0 + tid;
        out_ts[(b << 6) + 63] =
            aldf(&tspart[b]) + aldf(&tspart[512 + b]) +
            aldf(&tspart[1024 + b]) + aldf(&tspart[1536 + b]) + tsb2;
    }
}

// ---------------------------------------------------------------------------
// fp32 GEMM (latent section) — unchanged.
// ---------------------------------------------------------------------------
__device__ __forceinline__ int perm_src(int np) {
    int g = (np & 63) >> 4;
    int cell = ((np >> 6) << 4) + (np & 15);
    return (g << 9) + cell;
}

__global__ __launch_bounds__(256) void gemm_tn(
    const float* __restrict__ A, const float* __restrict__ Am,
    const float* __restrict__ Av, const float* __restrict__ Ae, int lda,
    const float* __restrict__ W1p, int ldw1,
    const float* __restrict__ W2p, int ldw2,
    int N, int K,
    const float* __restrict__ b1p, const float* __restrict__ b2p,
    float* __restrict__ C1, float* __restrict__ C2, int ldc,
    int relu, int permW)
{
    const float* W = W1p; int ldw = ldw1;
    const float* bias = b1p; float* C = C1;
    if (blockIdx.z == 1) { W = W2p; ldw = ldw2; bias = b2p; C = C2; }

    __shared__ __align__(16) float As[32][68];
    __shared__ __align__(16) float Ws[32][68];
    const int tid = threadIdx.x;
    const int tx = tid & 15, ty = tid >> 4;
    const int row0 = blockIdx.y << 6;
    const int col0 = blockIdx.x << 6;

    float acc[4][4] = {};

    for (int k0 = 0; k0 < K; k0 += 32) {
        #pragma unroll
        for (int s = 0; s < 2; ++s) {
            int f = tid + (s << 8);
            int rr = f >> 3;
            int kq = (f & 7) << 2;
            int k = k0 + kq;
            float4 v = make_float4(0.f, 0.f, 0.f, 0.f);
            size_t ro = (size_t)(row0 + rr) * (size_t)lda;
            if (Am) {
                if (k + 3 < K) {
                    float4 m = *(const float4*)(Am + ro + k);
                    float4 vv = *(const float4*)(Av + ro + k);
                    float4 e = *(const float4*)(Ae + ro + k);
                    v.x = fmaf(vv.x, e.x, m.x); v.y = fmaf(vv.y, e.y, m.y);
                    v.z = fmaf(vv.z, e.z, m.z); v.w = fmaf(vv.w, e.w, m.w);
                } else {
                    if (k + 0 < K) v.x = fmaf(Av[ro + k], Ae[ro + k], Am[ro + k]);
                    if (k + 1 < K) v.y = fmaf(Av[ro + k + 1], Ae[ro + k + 1], Am[ro + k + 1]);
                    if (k + 2 < K) v.z = fmaf(Av[ro + k + 2], Ae[ro + k + 2], Am[ro + k + 2]);
                }
            } else {
                const float* ap = A + ro;
                if (k + 3 < K) v = *(const float4*)(ap + k);
                else {
                    if (k + 0 < K) v.x = ap[k + 0];
                    if (k + 1 < K) v.y = ap[k + 1];
                    if (k + 2 < K) v.z = ap[k + 2];
                }
            }
            As[kq + 0][rr] = v.x; As[kq + 1][rr] = v.y;
            As[kq + 2][rr] = v.z; As[kq + 3][rr] = v.w;
        }
        #pragma unroll
        for (int s = 0; s < 2; ++s) {
            int f = tid + (s << 8);
            int rr = f >> 3;
            int kq = (f & 7) << 2;
            int k = k0 + kq;
            int n = col0 + rr;
            float4 v = make_float4(0.f, 0.f, 0.f, 0.f);
            if (n < N) {
                int nsrc = permW ? perm_src(n) : n;
                const float* wp = W + (size_t)nsrc * (size_t)ldw;
                if (k + 3 < K) v = *(const float4*)(wp + k);
                else {
                    if (k + 0 < K) v.x = wp[k + 0];
                    if (k + 1 < K) v.y = wp[k + 1];
                    if (k + 2 < K) v.z = wp[k + 2];
                }
            }
            Ws[kq + 0][rr] = v.x; Ws[kq + 1][rr] = v.y;
            Ws[kq + 2][rr] = v.z; Ws[kq + 3][rr] = v.w;
        }
        __syncthreads();
        #pragma unroll
        for (int k = 0; k < 32; ++k) {
            float4 av = *(const float4*)&As[k][ty << 2];
            float4 bv = *(const float4*)&Ws[k][tx << 2];
            acc[0][0] = fmaf(av.x, bv.x, acc[0][0]);
            acc[0][1] = fmaf(av.x, bv.y, acc[0][1]);
            acc[0][2] = fmaf(av.x, bv.z, acc[0][2]);
            acc[0][3] = fmaf(av.x, bv.w, acc[0][3]);
            acc[1][0] = fmaf(av.y, bv.x, acc[1][0]);
            acc[1][1] = fmaf(av.y, bv.y, acc[1][1]);
            acc[1][2] = fmaf(av.y, bv.z, acc[1][2]);
            acc[1][3] = fmaf(av.y, bv.w, acc[1][3]);
            acc[2][0] = fmaf(av.z, bv.x, acc[2][0]);
            acc[2][1] = fmaf(av.z, bv.y, acc[2][1]);
            acc[2][2] = fmaf(av.z, bv.z, acc[2][2]);
            acc[2][3] = fmaf(av.z, bv.w, acc[2][3]);
            acc[3][0] = fmaf(av.w, bv.x, acc[3][0]);
            acc[3][1] = fmaf(av.w, bv.y, acc[3][1]);
            acc[3][2] = fmaf(av.w, bv.z, acc[3][2]);
            acc[3][3] = fmaf(av.w, bv.w, acc[3][3]);
        }
        __syncthreads();
    }

    #pragma unroll
    for (int i = 0; i < 4; ++i) {
        int rr = row0 + (ty << 2) + i;
        float* cp = C + (size_t)rr * (size_t)ldc;
        #pragma unroll
        for (int j = 0; j < 4; ++j) {
            int cc = col0 + (tx << 2) + j;
            if (cc < N) {
                float v = acc[i][j];
                if (bias) v += bias[cc];
                if (relu) v = fmaxf(v, 0.f);
                cp[cc] = v;
            }
        }
    }
}

// ---------------------------------------------------------------------------
// One-shot packing — unchanged.
// ---------------------------------------------------------------------------
#define N_WE (G4 * 608)
#define N_WT (G4 * 608)
#define N_W1 (256 * 512)
#define N_E2 (64 * 512)
__global__ void pack_all(
    u16* __restrict__ Weh, u16* __restrict__ Wel,
    u16* __restrict__ Wth, u16* __restrict__ Wtl,
    u16* __restrict__ W1h,
    u16* __restrict__ E2h, u16* __restrict__ E2l,
    float* __restrict__ be, float* __restrict__ ba, float* __restrict__ bt,
    const float* __restrict__ eWih, const float* __restrict__ eWhh,
    const float* __restrict__ tWih, const float* __restrict__ tWhh,
    const float* __restrict__ ts1W, const float* __restrict__ e2W,
    const float* __restrict__ ebih, const float* __restrict__ ebhh,
    const float* __restrict__ abih, const float* __restrict__ abhh,
    const float* __restrict__ tbih, const float* __restrict__ tbhh)
{
    int idx = blockIdx.x * 256 + threadIdx.x;
    if (idx < N_WE) {
        int np = idx / 608, k = idx - np * 608;
        int n = perm_src(np);
        float v = 0.f;
        if (k < 65) v = eWih[n * 65 + k];
        else if (k < 577) v = eWhh[(n << 9) + k - 65];
        u16 h = f2bf(v); Weh[idx] = h; Wel[idx] = f2bf(v - bf2f(h));
        return;
    }
    idx -= N_WE;
    if (idx < N_WT) {
        int np = idx / 608, k = idx - np * 608;
        int n = perm_src(np);
        float v = 0.f;
        if (k < 512) v = tWhh[(n << 9) + k];
        else if (k < 576) v = tWih[n * 585 + 520 + (k - 512)];
        else if (k == 576) v = tWih[n * 585 + 584];
        u16 h = f2bf(v); Wth[idx] = h; Wtl[idx] = f2bf(v - bf2f(h));
        return;
    }
    idx -= N_WT;
    if (idx < N_W1) {
        W1h[idx] = f2bf(ts1W[idx]);
        return;
    }
    idx -= N_W1;
    if (idx < N_E2) {
        float v = e2W[idx];
        u16 h = f2bf(v); E2h[idx] = h; E2l[idx] = f2bf(v - bf2f(h));
        return;
    }
    idx -= N_E2;
    if (idx < G4) {
        int n = perm_src(idx);
        be[idx] = ebih[n] + ebhh[n];
        ba[idx] = abih[n] + abhh[n];
        bt[idx] = tbih[n] + tbhh[n];
    }
}

// ---------------------------------------------------------------------------
// init_all: interleaved X0 buffers, lens, attr->tcat, barrier counters.
// ---------------------------------------------------------------------------
__global__ __launch_bounds__(256) void init_all(
    u32* __restrict__ xe0, u32* __restrict__ xe1,
    int* __restrict__ lens, float* __restrict__ tcat,
    u32* __restrict__ xa0, u32* __restrict__ xt0,
    const int* __restrict__ acts, const float* __restrict__ tsv,
    const float* __restrict__ act_emb,
    const int* __restrict__ attr_cat, const float* __restrict__ attr_num,
    const float* __restrict__ attr_emb,
    const float* __restrict__ a2aW, const float* __restrict__ a2ab,
    int* __restrict__ bars)
{
    int b = blockIdx.x, tid = threadIdx.x;
    if (b == 0) {
        for (int j = tid; j < 1024; j += 256)
            __hip_atomic_store(&bars[j], 0, __ATOMIC_RELAXED, __HIP_MEMORY_SCOPE_AGENT);
    }
    for (int j = tid; j < 608; j += 256) {
        float v = 0.f;
        if (j < 64) v = act_emb[acts[b << 6] * 64 + j];
        else if (j == 64) v = tsv[b << 6];
        xe0[b * 608 + j] = packbf(v);
        if (j >= 577) xe1[b * 608 + j] = 0;
    }
    for (int j = tid; j < CF; j += 256) {
        xt0[(b << 9) + j] = 0;
    }
    for (int j = tid; j < 576; j += 256) {
        float v = (j < 64) ? act_emb[63 * 64 + j] : 0.f;
        xa0[b * 576 + j] = packbf(v);
    }
    if (tid < 64) {
        int v = acts[(b << 6) + tid];
        int m = v;
        #pragma unroll
        for (int off = 32; off; off >>= 1) m = max(m, __shfl_xor(m, off));
        unsigned long long mask = __ballot(v == m);
        if (tid == 0) lens[b] = __ffsll(mask) - 1;
    }
    if (tid < 8) {
        const float* wr = a2aW + tid * 17;
        const float* em = attr_emb + attr_cat[b] * 16;
        float s = a2ab[tid];
        #pragma unroll
        for (int k = 0; k < 16; ++k) s = fmaf(em[k], wr[k], s);
        s = fmaf(attr_num[b], wr[16], s);
        tcat[b * TDIM + tid] = fmaxf(s, 0.f);
    }
}

__global__ __launch_bounds__(64) void attr_heads(
    const float* __restrict__ hid1, const float* __restrict__ hid2,
    const float* __restrict__ tc2W, const float* __restrict__ tc2b,
    const float* __restrict__ tn2W, const float* __restrict__ tn2b,
    float* __restrict__ out_cat, float* __restrict__ out_num) {
    __shared__ __align__(16) float h1[260], h2[260], sl[10];
    int b = blockIdx.x, tid = threadIdx.x;
    for (int k = tid; k < 260; k += 64) {
        h1[k] = hid1[b * 260 + k];
        h2[k] = hid2[b * 260 + k];
    }
    __syncthreads();
    if (tid < 10) {
        float l = tc2b[tid];
        const float* wr = tc2W + tid * 260;
        for (int k = 0; k < 260; ++k) l = fmaf(h1[k], wr[k], l);
        sl[tid] = l;
    }
    __syncthreads();
    if (tid < 10) {
        float m = sl[0];
        for (int i = 1; i < 10; ++i) m = fmaxf(m, sl[i]);
        float ssum = 0.f;
        for (int i = 0; i < 10; ++i) ssum += expf(sl[i] - m);
        out_cat[b * 10 + tid] = expf(sl[tid] - m) / ssum;
    }
    float p = 0.f;
    for (int k = tid; k < 260; k += 64) p = fmaf(h2[k], tn2W[k], p);
    #pragma unroll
    for (int off = 32; off; off >>= 1) p += __shfl_xor(p, off);
    if (tid == 0) out_num[b] = 1.f / (1.f + expf(-(p + tn2b[0])));
}

// ---------------------------------------------------------------------------
extern "C" void kernel_launch(void* const* d_in, const int* in_sizes, int n_in,
                              void* d_out, int out_size, void* d_ws, size_t ws_size,
                              hipStream_t stream) {
    const int*   attr_cat = (const int*)  d_in[0];
    const float* attr_num = (const float*)d_in[1];
    const int*   acts     = (const int*)  d_in[2];
    const float* tsv      = (const float*)d_in[3];
    const float* eps      = (const float*)d_in[4];
    const float* attr_emb = (const float*)d_in[5];
    const float* a2a_W    = (const float*)d_in[6];
    const float* a2a_b    = (const float*)d_in[7];
    const float* act_emb  = (const float*)d_in[8];
    const float* eWih     = (const float*)d_in[9];
    const float* eWhh     = (const float*)d_in[10];
    const float* ebih     = (const float*)d_in[11];
    const float* ebhh     = (const float*)d_in[12];
    const float* mean_W   = (const float*)d_in[13];
    const float* mean_b   = (const float*)d_in[14];
    const float* var_W    = (const float*)d_in[15];
    const float* var_b    = (const float*)d_in[16];
    const float* z2t_W    = (const float*)d_in[17];
    const float* z2t_b    = (const float*)d_in[18];
    const float* tc1_W    = (const float*)d_in[19];
    const float* tc1_b    = (const float*)d_in[20];
    const float* tc2_W    = (const float*)d_in[21];
    const float* tc2_b    = (const float*)d_in[22];
    const float* tn1_W    = (const float*)d_in[23];
    const float* tn1_b    = (const float*)d_in[24];
    const float* tn2_W    = (const float*)d_in[25];
    const float* tn2_b    = (const float*)d_in[26];
    const float* aWih     = (const float*)d_in[27];
    const float* aWhh     = (const float*)d_in[28];
    const float* abih     = (const float*)d_in[29];
    const float* abhh     = (const float*)d_in[30];
    const float* tWih     = (const float*)d_in[31];
    const float* tWhh     = (const float*)d_in[32];
    const float* tbih     = (const float*)d_in[33];
    const float* tbhh     = (const float*)d_in[34];
    const float* e2act_W  = (const float*)d_in[35];
    const float* e2act_b  = (const float*)d_in[36];
    const float* ts1_W    = (const float*)d_in[37];
    const float* ts1_b    = (const float*)d_in[38];
    const float* ts2_W    = (const float*)d_in[39];
    const float* ts2_b    = (const float*)d_in[40];

    float* out = (float*)d_out;
    float* out_cat  = out;
    float* out_num  = out + 5120;
    float* out_acts = out + 5632;
    float* out_ts   = out + 2102784;
    float* outm     = out + 2135552;
    float* outv     = out + 2201088;

    char* w = (char*)d_ws;
    auto alloc = [&](size_t bytes) { char* p = w; w += (bytes + 255) & ~(size_t)255; return p; };
    // --- persistent region ---
    u16*   Wt_hi  = (u16*)alloc((size_t)G4 * 608 * 2);
    u16*   Wt_lo  = (u16*)alloc((size_t)G4 * 608 * 2);
    u16*   W1h    = (u16*)alloc(256 * 512 * 2);
    u16*   E2h    = (u16*)alloc(64 * 512 * 2);
    u16*   E2l    = (u16*)alloc(64 * 512 * 2);
    float* bias_e = (float*)alloc(G4 * 4);
    float* bias_a = (float*)alloc(G4 * 4);
    float* bias_t = (float*)alloc(G4 * 4);
    float* base_a = (float*)alloc((size_t)B * G4 * 4);
    float* base_t = (float*)alloc((size_t)B * G4 * 4);
    u32*   Xa32   = (u32*)alloc((size_t)2 * B * 576 * 4);
    u32*   Xt32   = (u32*)alloc((size_t)2 * B * 512 * 4);
    float* tcat   = (float*)alloc((size_t)B * TDIM * 4);
    float* t_rec  = (float*)alloc((size_t)B * TDIM * 4);
    float* hid1   = (float*)alloc((size_t)B * 260 * 4);
    float* hid2   = (float*)alloc((size_t)B * 260 * 4);
    int*   lens   = (int*)alloc(512 * 4);
    float* partial4 = (float*)alloc(4 * 512 * 4);
    int*   bars   = (int*)alloc(4096);  // [by*32]=enc, [256+by*32]=dec, [512]=global
    // --- phase overlay: encoder {We,Xe} / decoder {Wa} ---
    char* phase = w;
    u16*   We_hi  = (u16*)(phase);
    u16*   We_lo  = (u16*)(phase + (size_t)G4 * 608 * 2);
    u32*   Xe32   = (u32*)(phase + (size_t)2 * G4 * 608 * 2);
    u16*   Wa_hi  = (u16*)(phase);
    u16*   Wa_lo  = (u16*)(phase + (size_t)G4 * 576 * 2);
    (void)ws_size; (void)in_sizes; (void)n_in; (void)out_size;

    // ---- prep (2 launches) ----
    {
        int total = N_WE + N_WT + N_W1 + N_E2 + G4;
        pack_all<<<(total + 255) / 256, 256, 0, stream>>>(
            We_hi, We_lo, Wt_hi, Wt_lo, W1h, E2h, E2l,
            bias_e, bias_a, bias_t,
            eWih, eWhh, tWih, tWhh, ts1_W, e2act_W,
            ebih, ebhh, abih, abhh, tbih, tbhh);
    }
    init_all<<<B, 256, 0, stream>>>(
        Xe32, Xe32 + (size_t)B * 608,
        lens, tcat, Xa32, Xt32,
        acts, tsv, act_emb, attr_cat, attr_num, attr_emb, a2a_W, a2a_b,
        bars);

    // ---- encoder (1 persistent launch, 63 per-by barriers) ----
    enc_coop<<<dim3(32, 8), 512, 0, stream>>>(
        Xe32, We_hi, We_lo, bias_e, tcat, lens, acts, tsv, act_emb,
        bars);

    // ---- latent (5 launches) ----
    gemm_tn<<<dim3(2, 8, 2), 256, 0, stream>>>(
        tcat, nullptr, nullptr, nullptr, TDIM, mean_W, TDIM, var_W, TDIM,
        ZD, TDIM, mean_b, var_b, outm, outv, ZD, 0, 0);
    gemm_tn<<<dim3(9, 8, 1), 256, 0, stream>>>(
        nullptr, outm, outv, eps, ZD, z2t_W, ZD, nullptr, 0,
        TDIM, ZD, z2t_b, nullptr, t_rec, nullptr, TDIM, 1, 0);
    gemm_tn<<<dim3(5, 8, 2), 256, 0, stream>>>(
        t_rec, nullptr, nullptr, nullptr, TDIM, tc1_W, TDIM, tn1_W, TDIM,
        260, TDIM, tc1_b, tn1_b, hid1, hid2, 260, 1, 0);
    attr_heads<<<B, 64, 0, stream>>>(hid1, hid2, tc2_W, tc2_b, tn2_W, tn2_b, out_cat, out_num);
    gemm_tn<<<dim3(32, 8, 2), 256, 0, stream>>>(
        t_rec, nullptr, nullptr, nullptr, TDIM, aWih, 584, tWih, 585,
        G4, TDIM, bias_a, bias_t, base_a, base_t, G4, 0, 1);

    // ---- decoder (1 persistent launch) ----
    dec_coop<<<dim3(32, 8), 512, 0, stream>>>(
        Xa32, Wa_hi, Wa_lo, aWih, aWhh, base_a,
        Xt32, Wt_hi, Wt_lo, base_t,
        E2h, E2l, e2act_b, act_emb, out_acts, out_ts,
        W1h, ts1_b, ts2_W, ts2_b, partial4,
        bars);
}

// Round 14
// 4716.511 us; speedup vs baseline: 1.0108x; 1.0108x over previous
//
#include <hip/hip_runtime.h>
#include <math.h>

// ---------------------------------------------------------------------------
// VAE_14482629722138 — round 19: REVERT to round-15 (best verified, 4729us).
// Plateau evidence: prefetch 2->4 (-3%), 2 waves/SIMD (-2%), producer/
// consumer (0%), LDS-only K-loop barriers (0%) — the ~790ns/iter floor is
// LDS-throughput/structural (40 b128 reads + 16 writes per iter, B read 4x
// redundantly by the 1x4 wave decomposition), fixable only by a 32x32-MFMA
// 2x2-tile rewrite of all epilogues (high risk, out of budget).
// Config: persistent enc/dec kernels, per-by fence-free barriers,
// MALL-coherent interleaved-u32 X buffers, LDS-staged gemm with 4-deep
// register prefetch, 256 threads/block. B=512, T=64, CF=512, TDIM=520.
// ---------------------------------------------------------------------------

#define B 512
#define TT 64
#define CF 512
#define G4 2048
#define ZD 128
#define TDIM 520

typedef unsigned short u16;
typedef unsigned int u32;
typedef unsigned long long u64;
typedef short bf16x8 __attribute__((ext_vector_type(8)));
typedef float f32x4 __attribute__((ext_vector_type(4)));

__device__ __forceinline__ float sigm(float x) { return 1.f / (1.f + expf(-x)); }
__device__ __forceinline__ u16 f2bf(float f) {
    unsigned u = __float_as_uint(f);
    u += 0x7fffu + ((u >> 16) & 1u);
    return (u16)(u >> 16);
}
__device__ __forceinline__ float bf2f(u16 s) { return __uint_as_float(((unsigned)s) << 16); }
__device__ __forceinline__ u32 packbf(float v) {
    u16 hh = f2bf(v);
    u16 hl = f2bf(v - bf2f(hh));
    return (u32)hh | ((u32)hl << 16);
}

// MALL-coherent (agent-scope, relaxed) accessors — bypass non-coherent L2s.
__device__ __forceinline__ void ast32(u32* p, u32 v) {
    __hip_atomic_store(p, v, __ATOMIC_RELAXED, __HIP_MEMORY_SCOPE_AGENT);
}
__device__ __forceinline__ u64 ald64(const u64* p) {
    return __hip_atomic_load(p, __ATOMIC_RELAXED, __HIP_MEMORY_SCOPE_AGENT);
}
__device__ __forceinline__ void astf(float* p, float v) {
    __hip_atomic_store(p, v, __ATOMIC_RELAXED, __HIP_MEMORY_SCOPE_AGENT);
}
__device__ __forceinline__ float aldf(const float* p) {
    return __hip_atomic_load(p, __ATOMIC_RELAXED, __HIP_MEMORY_SCOPE_AGENT);
}

// Unpack 4 u64 (8 interleaved elements) -> hi-u16x8 and lo-u16x8 vectors.
__device__ __forceinline__ void unpk8(u64 a, u64 b, u64 c, u64 d,
                                      uint4& hi, uint4& lo) {
    u32 a0 = (u32)a, a1 = (u32)(a >> 32);
    u32 b0 = (u32)b, b1 = (u32)(b >> 32);
    u32 c0 = (u32)c, c1 = (u32)(c >> 32);
    u32 d0 = (u32)d, d1 = (u32)(d >> 32);
    hi.x = (a0 & 0xffffu) | (a1 << 16);  lo.x = (a0 >> 16) | (a1 & 0xffff0000u);
    hi.y = (b0 & 0xffffu) | (b1 << 16);  lo.y = (b0 >> 16) | (b1 & 0xffff0000u);
    hi.z = (c0 & 0xffffu) | (c1 << 16);  lo.z = (c0 >> 16) | (c1 & 0xffff0000u);
    hi.w = (d0 & 0xffffu) | (d1 << 16);  lo.w = (d0 >> 16) | (d1 & 0xffff0000u);
}

// Fence-free per-group barrier: RELEASE add + RELAXED spin; no cache ops.
__device__ __forceinline__ void gsync_fast(int* bar, int target) {
    __syncthreads();
    if (threadIdx.x == 0) {
        __hip_atomic_fetch_add(bar, 1, __ATOMIC_RELEASE, __HIP_MEMORY_SCOPE_AGENT);
        while (__hip_atomic_load(bar, __ATOMIC_RELAXED, __HIP_MEMORY_SCOPE_AGENT) < target)
            __builtin_amdgcn_s_sleep(2);
    }
    __syncthreads();
}

// Full barrier (threadfence both sides) — once at dec prologue.
__device__ __forceinline__ void gsync_full(int* bar, int target) {
    __syncthreads();
    if (threadIdx.x == 0) {
        __threadfence();
        __hip_atomic_fetch_add(bar, 1, __ATOMIC_ACQ_REL, __HIP_MEMORY_SCOPE_AGENT);
        while (__hip_atomic_load(bar, __ATOMIC_ACQUIRE, __HIP_MEMORY_SCOPE_AGENT) < target)
            __builtin_amdgcn_s_sleep(2);
        __threadfence();
    }
    __syncthreads();
}

struct __align__(16) GemmShared {
    u16 A[2][2][64][40];   // [dbuf][hi/lo][row][k(+pad)]
    u16 Bw[2][2][64][40];
};

// Prefetch register set — named fields only (no dynamic reg-array indexing).
struct Pref { u64 a0, a1, a2, a3; uint4 bh, bl; };

template<int TERMS>
__device__ __forceinline__ void pf_issue(Pref& p, const u64* xp,
        const u16* wph, const u16* wpl, int it) {
    const int k = it << 5;
    const u64* xq = xp + (k >> 1);
    p.a0 = ald64(xq); p.a1 = ald64(xq + 1);
    p.a2 = ald64(xq + 2); p.a3 = ald64(xq + 3);
    p.bh = *(const uint4*)(wph + k);
    if (TERMS == 3) p.bl = *(const uint4*)(wpl + k);
}

template<int TERMS>
__device__ __forceinline__ void pf_write(GemmShared& sh, const Pref& p,
        int nxt, int srr, int skq) {
    uint4 hi, lo; unpk8(p.a0, p.a1, p.a2, p.a3, hi, lo);
    *(uint4*)&sh.A[nxt][0][srr][skq] = hi;
    *(uint4*)&sh.A[nxt][1][srr][skq] = lo;
    *(uint4*)&sh.Bw[nxt][0][srr][skq] = p.bh;
    if (TERMS == 3) *(uint4*)&sh.Bw[nxt][1][srr][skq] = p.bl;
}

template<int TERMS>
__device__ __forceinline__ void pf_comp(GemmShared& sh, int cur,
        int row, int ko, int fr, f32x4 acc[4]) {
    bf16x8 ah = *(const bf16x8*)&sh.A[cur][0][row][ko];
    bf16x8 al = *(const bf16x8*)&sh.A[cur][1][row][ko];
    #pragma unroll
    for (int nt = 0; nt < 4; ++nt) {
        bf16x8 bh = *(const bf16x8*)&sh.Bw[cur][0][(nt << 4) + fr][ko];
        acc[nt] = __builtin_amdgcn_mfma_f32_16x16x32_bf16(ah, bh, acc[nt], 0, 0, 0);
        if (TERMS == 3) {
            bf16x8 bl = *(const bf16x8*)&sh.Bw[cur][1][(nt << 4) + fr][ko];
            acc[nt] = __builtin_amdgcn_mfma_f32_16x16x32_bf16(ah, bl, acc[nt], 0, 0, 0);
        }
        acc[nt] = __builtin_amdgcn_mfma_f32_16x16x32_bf16(al, bh, acc[nt], 0, 0, 0);
    }
}

// ---------------------------------------------------------------------------
// 64x64 MFMA tile, K multiple of 32, 4-deep register prefetch into a 2-slot
// LDS double buffer. A: interleaved-u32 coherent buffer (stride lda);
// B: u16 hi/lo rows (row stride ldb). Struct X=(i%4) written (for iter i+1)
// at end of iter i, reissued for iter i+5.
// acc[nt][r]: row = ws*16+quad*4+r, col = nt*16+fr.
// ---------------------------------------------------------------------------
template<int TERMS>
__device__ __forceinline__ void gemm64i(
    GemmShared& sh,
    const u32* __restrict__ A32, int lda,
    const u16* __restrict__ Bh, const u16* __restrict__ Bl, int K, int ldb,
    f32x4 acc[4])
{
    const int tid = threadIdx.x;
    const int lane = tid & 63, ws = tid >> 6;
    const int fr = lane & 15, quad = lane >> 4, ko = quad << 3;
    const int srr = tid >> 2, skq = (tid & 3) << 3;
    const int row = (ws << 4) + fr;

    const u64* xp = (const u64*)(A32 + srr * lda + skq);   // 8B-aligned
    const u16* wph = Bh + srr * ldb + skq;
    const u16* wpl = (TERMS == 3) ? (Bl + srr * ldb + skq) : (const u16*)0;

    const int niter = K >> 5;
    {   // iter 0 staged directly
        u64 d0 = ald64(xp), d1 = ald64(xp + 1), d2 = ald64(xp + 2), d3 = ald64(xp + 3);
        uint4 hi, lo; unpk8(d0, d1, d2, d3, hi, lo);
        *(uint4*)&sh.A[0][0][srr][skq] = hi;
        *(uint4*)&sh.A[0][1][srr][skq] = lo;
        *(uint4*)&sh.Bw[0][0][srr][skq] = *(const uint4*)(wph);
        if (TERMS == 3) *(uint4*)&sh.Bw[0][1][srr][skq] = *(const uint4*)(wpl);
    }
    Pref pA, pB, pC, pD;
    if (niter > 1) pf_issue<TERMS>(pA, xp, wph, wpl, 1);
    if (niter > 2) pf_issue<TERMS>(pB, xp, wph, wpl, 2);
    if (niter > 3) pf_issue<TERMS>(pC, xp, wph, wpl, 3);
    if (niter > 4) pf_issue<TERMS>(pD, xp, wph, wpl, 4);
    __syncthreads();

    int i = 0;
    for (;;) {
        // i % 4 == 0 : slot 0, struct A
        pf_comp<TERMS>(sh, 0, row, ko, fr, acc);
        if (i + 1 < niter) {
            pf_write<TERMS>(sh, pA, 1, srr, skq);
            if (i + 5 < niter) pf_issue<TERMS>(pA, xp, wph, wpl, i + 5);
        }
        __syncthreads();
        if (++i >= niter) break;
        // i % 4 == 1 : slot 1, struct B
        pf_comp<TERMS>(sh, 1, row, ko, fr, acc);
        if (i + 1 < niter) {
            pf_write<TERMS>(sh, pB, 0, srr, skq);
            if (i + 5 < niter) pf_issue<TERMS>(pB, xp, wph, wpl, i + 5);
        }
        __syncthreads();
        if (++i >= niter) break;
        // i % 4 == 2 : slot 0, struct C
        pf_comp<TERMS>(sh, 0, row, ko, fr, acc);
        if (i + 1 < niter) {
            pf_write<TERMS>(sh, pC, 1, srr, skq);
            if (i + 5 < niter) pf_issue<TERMS>(pC, xp, wph, wpl, i + 5);
        }
        __syncthreads();
        if (++i >= niter) break;
        // i % 4 == 3 : slot 1, struct D
        pf_comp<TERMS>(sh, 1, row, ko, fr, acc);
        if (i + 1 < niter) {
            pf_write<TERMS>(sh, pD, 0, srr, skq);
            if (i + 5 < niter) pf_issue<TERMS>(pD, xp, wph, wpl, i + 5);
        }
        __syncthreads();
        if (++i >= niter) break;
    }
}

// One 64-col strip of the ts head (relu per hidden unit -> N-split exact).
__device__ __forceinline__ void ts_strip(
    GemmShared& sh, const u32* __restrict__ Xt32r,
    const u16* __restrict__ W1h, const float* __restrict__ b1,
    const float* __restrict__ w2, int ncg, float s[4])
{
    const int lane = threadIdx.x & 63;
    const int fr = lane & 15;
    f32x4 ac[4] = {};
    gemm64i<2>(sh, Xt32r, 512, W1h + (size_t)(ncg << 6) * 512, nullptr, 512, 512, ac);
    s[0] = s[1] = s[2] = s[3] = 0.f;
    #pragma unroll
    for (int nt = 0; nt < 4; ++nt) {
        int j = (ncg << 6) + (nt << 4) + fr;
        float b1v = b1[j], w2v = w2[j];
        s[0] += fmaxf(ac[nt][0] + b1v, 0.f) * w2v;
        s[1] += fmaxf(ac[nt][1] + b1v, 0.f) * w2v;
        s[2] += fmaxf(ac[nt][2] + b1v, 0.f) * w2v;
        s[3] += fmaxf(ac[nt][3] + b1v, 0.f) * w2v;
    }
    #pragma unroll
    for (int off = 1; off < 16; off <<= 1) {
        s[0] += __shfl_xor(s[0], off);
        s[1] += __shfl_xor(s[1], off);
        s[2] += __shfl_xor(s[2], off);
        s[3] += __shfl_xor(s[3], off);
    }
}

// ---------------------------------------------------------------------------
// Persistent encoder: 64 steps, one per-by barrier per step.
// ---------------------------------------------------------------------------
__global__ __launch_bounds__(256, 1) void enc_coop(
    u32* __restrict__ Xe32,                     // 2 x B x 608 interleaved
    const u16* __restrict__ Weh, const u16* __restrict__ Wel,
    const float* __restrict__ biaspk,
    float* __restrict__ tcat, const int* __restrict__ lens,
    const int* __restrict__ acts, const float* __restrict__ tsv,
    const float* __restrict__ act_emb, int* __restrict__ bars)
{
    __shared__ GemmShared sh;
    const int bx = blockIdx.x, by = blockIdx.y, row0 = by << 6;
    const int tid = threadIdx.x, lane = tid & 63, ws = tid >> 6;
    const int fr = lane & 15, quad = lane >> 4;
    const int cell = (bx << 4) + fr;
    const int rbase = row0 + (ws << 4) + (quad << 2);
    int* bar = bars + by * 32;
    int gen = 0;

    float bb[4], ce[4] = {0.f, 0.f, 0.f, 0.f};
    int lm1[4];
    #pragma unroll
    for (int g = 0; g < 4; ++g) bb[g] = biaspk[(bx << 6) + (g << 4) + fr];
    #pragma unroll
    for (int r = 0; r < 4; ++r) lm1[r] = lens[rbase + r] - 1;

    for (int t = 0; t < TT; ++t) {
        const u32* xc = Xe32 + (size_t)(t & 1) * B * 608;
        u32* xn = Xe32 + (size_t)((t + 1) & 1) * B * 608;

        f32x4 acc[4] = {};
        gemm64i<3>(sh, xc + (size_t)row0 * 608, 608,
                   Weh + (size_t)(bx << 6) * 608, Wel + (size_t)(bx << 6) * 608,
                   608, 608, acc);

        #pragma unroll
        for (int r = 0; r < 4; ++r) {
            int b = rbase + r;
            float gi = acc[0][r] + bb[0], gf = acc[1][r] + bb[1];
            float gg = acc[2][r] + bb[2], go = acc[3][r] + bb[3];
            float cn = sigm(gf) * ce[r] + sigm(gi) * tanhf(gg);
            ce[r] = cn;
            float h = sigm(go) * tanhf(cn);
            ast32(&xn[b * 608 + 65 + cell], packbf(h));
            if (t == lm1[r]) tcat[b * TDIM + 8 + cell] = h;
        }
        if (t < TT - 1) {
            // next-x staging: each (bx,by) covers 2 rows x 65 cols
            for (int idx = tid; idx < 130; idx += 256) {
                int hi2 = (idx >= 65);
                int r = (bx << 1) + hi2, cc = idx - hi2 * 65;
                int b = row0 + r;
                float v = (cc < 64) ? act_emb[acts[(b << 6) + t + 1] * 64 + cc]
                                    : tsv[(b << 6) + t + 1];
                ast32(&xn[b * 608 + cc], packbf(v));
            }
            gsync_fast(bar, (++gen) * 32);
        }
    }
}

// ---------------------------------------------------------------------------
// Persistent decoder: Wa pack (global full barrier once), then 64 steps with
// 2 per-by barriers each, then ts tail.
// ---------------------------------------------------------------------------
__global__ __launch_bounds__(256, 1) void dec_coop(
    u32* __restrict__ Xa32,                     // 2 x B x 576 interleaved
    u16* Wah, u16* Wal,
    const float* __restrict__ aWih, const float* __restrict__ aWhh,
    const float* __restrict__ base_a,
    u32* __restrict__ Xt32,                     // 2 x B x 512 interleaved
    const u16* __restrict__ Wth, const u16* __restrict__ Wtl,
    const float* __restrict__ base_t,
    const u16* __restrict__ E2h, const u16* __restrict__ E2l,
    const float* __restrict__ e2b, const float* __restrict__ act_emb,
    float* __restrict__ out_acts, float* __restrict__ out_ts,
    const u16* __restrict__ W1h, const float* __restrict__ b1,
    const float* __restrict__ w2, const float* __restrict__ b2p,
    float* __restrict__ tspart, int* __restrict__ bars)
{
    __shared__ GemmShared sh;
    __shared__ u16 ae2h[64][72];
    __shared__ u16 ae2l[64][72];
    const int bx = blockIdx.x, by = blockIdx.y, row0 = by << 6;
    const int tid = threadIdx.x, lane = tid & 63, ws = tid >> 6;
    const int fr = lane & 15, quad = lane >> 4;
    const int srr = tid >> 2, skq = (tid & 3) << 3;
    const bool bx0 = (bx == 0);
    const int cell = (bx << 4) + fr;
    const int rb0 = (ws << 4) + (quad << 2);
    const int rbase = row0 + rb0;
    const int arow = (ws << 4) + fr;
    const float tsb2 = b2p[0];
    int* barG = bars + 512;            // global (256 contenders), used once
    int* bar  = bars + 256 + by * 32;  // per-by (32 contenders)
    int gen = 0;

    // ---- prologue: pack Wa (plain stores; full fence publishes) ----
    {
        const int gtid = (((by << 5) + bx) << 8) + tid;
        for (int idx = gtid; idx < G4 * 576; idx += 32 * 8 * 256) {
            int np = idx / 576, k = idx - np * 576;
            int g = (np & 63) >> 4;
            int n = (g << 9) + (((np >> 6) << 4) + (np & 15));
            float v = (k < 64) ? aWih[n * 584 + 520 + k] : aWhh[(n << 9) + k - 64];
            u16 h = f2bf(v);
            Wah[idx] = h; Wal[idx] = f2bf(v - bf2f(h));
        }
    }

    float e2bv[4];
    float ca_r[4] = {0.f, 0.f, 0.f, 0.f}, ct_r[4] = {0.f, 0.f, 0.f, 0.f};
    #pragma unroll
    for (int nt = 0; nt < 4; ++nt) e2bv[nt] = e2b[(nt << 4) + fr];

    gsync_full(barG, 256);   // Wa visible; stale L2 lines evicted

    for (int t = 0; t < TT; ++t) {
        u32* xac = Xa32 + (size_t)(t & 1) * B * 576;
        u32* xan = Xa32 + (size_t)((t + 1) & 1) * B * 576;
        const u32* xtc = Xt32 + (size_t)(t & 1) * B * 512;
        u32* xtn = Xt32 + (size_t)((t + 1) & 1) * B * 512;

        // ============ phase 1: gemm_a + cell_a (+ ts strip on bx<4) ======
        {
            f32x4 acc[4] = {};
            gemm64i<3>(sh, xac + (size_t)row0 * 576, 576,
                       Wah + (size_t)(bx << 6) * 576, Wal + (size_t)(bx << 6) * 576,
                       576, 576, acc);
            #pragma unroll
            for (int r = 0; r < 4; ++r) {
                int b = rbase + r;
                const float* bp = base_a + (size_t)b * G4 + (bx << 6) + fr;
                float gi = acc[0][r] + bp[0], gf = acc[1][r] + bp[16];
                float gg = acc[2][r] + bp[32], go = acc[3][r] + bp[48];
                float cn = sigm(gf) * ca_r[r] + sigm(gi) * tanhf(gg);
                ca_r[r] = cn;
                float h = sigm(go) * tanhf(cn);
                ast32(&xan[b * 576 + 64 + cell], packbf(h));
            }
            if (bx < 4 && t > 0) {
                float s[4];
                ts_strip(sh, xtc + (size_t)row0 * 512, W1h, b1, w2, bx, s);
                if (fr == 0) {
                    #pragma unroll
                    for (int r = 0; r < 4; ++r) astf(&tspart[(bx << 9) + rbase + r], s[r]);
                }
            }
        }
        gsync_fast(bar, (++gen) * 32);

        // ============ phase 2: act head + gemm_t + cell_t ================
        if (t > 0 && bx == 1 && tid < 64) {
            int b = row0 + tid;
            out_ts[(b << 6) + t - 1] =
                aldf(&tspart[b]) + aldf(&tspart[512 + b]) +
                aldf(&tspart[1024 + b]) + aldf(&tspart[1536 + b]) + tsb2;
        }
        // tsc for this lane's staging row (hides under act head)
        float tsq = 0.f;
        if (t > 0) {
            int b = row0 + srr;
            tsq = aldf(&tspart[b]) + aldf(&tspart[512 + b]) +
                  aldf(&tspart[1024 + b]) + aldf(&tspart[1536 + b]) + tsb2;
        }
        {   // act head (block-local; reads h_a region of xan)
            f32x4 acc[4] = {};
            gemm64i<3>(sh, xan + (size_t)row0 * 576 + 64, 576, E2h, E2l, 512, 512, acc);
            #pragma unroll
            for (int r = 0; r < 4; ++r) {
                float l0 = acc[0][r] + e2bv[0], l1 = acc[1][r] + e2bv[1];
                float l2 = acc[2][r] + e2bv[2], l3 = acc[3][r] + e2bv[3];
                float m = fmaxf(fmaxf(l0, l1), fmaxf(l2, l3));
                #pragma unroll
                for (int off = 1; off < 16; off <<= 1) m = fmaxf(m, __shfl_xor(m, off));
                float e0 = expf(l0 - m), e1 = expf(l1 - m);
                float e2v = expf(l2 - m), e3 = expf(l3 - m);
                float sm = e0 + e1 + e2v + e3;
                #pragma unroll
                for (int off = 1; off < 16; off <<= 1) sm += __shfl_xor(sm, off);
                float bv = l0; int bc = fr;
                if (l1 > bv) { bv = l1; bc = 16 + fr; }
                if (l2 > bv) { bv = l2; bc = 32 + fr; }
                if (l3 > bv) { bv = l3; bc = 48 + fr; }
                #pragma unroll
                for (int off = 1; off < 16; off <<= 1) {
                    float ov = __shfl_xor(bv, off);
                    int oc = __shfl_xor(bc, off);
                    if (ov > bv || (ov == bv && oc < bc)) { bv = ov; bc = oc; }
                }
                int rl = rb0 + r, b = row0 + rl;
                if (bx0) {
                    float inv = 1.f / sm;
                    float* op = out_acts + (((size_t)(b << 6) + t) << 6);
                    op[fr] = e0 * inv; op[16 + fr] = e1 * inv;
                    op[32 + fr] = e2v * inv; op[48 + fr] = e3 * inv;
                }
                #pragma unroll
                for (int ci = 0; ci < 4; ++ci) {
                    int cc = (fr << 2) + ci;
                    float v = act_emb[(bc << 6) + cc];
                    u16 hh = f2bf(v), hl = f2bf(v - bf2f(hh));
                    ae2h[rl][cc] = hh; ae2l[rl][cc] = hl;
                    if (bx0) ast32(&xan[b * 576 + cc], ((u32)hh) | ((u32)hl << 16));
                }
            }
        }
        __syncthreads();

        // gemm_t: pipelined K=512 part (A = Xt), then 3 on-chip tail iters
        f32x4 acc[4] = {};
        gemm64i<3>(sh, xtc + (size_t)row0 * 512, 512,
                   Wth + (size_t)(bx << 6) * 608, Wtl + (size_t)(bx << 6) * 608,
                   512, 608, acc);
        {
            const u16* wph = Wth + (size_t)((bx << 6) + srr) * 608 + skq;
            const u16* wpl = Wtl + (size_t)((bx << 6) + srr) * 608 + skq;
            const int ko = quad << 3;
            for (int i = 16; i < 19; ++i) {
                int k0 = i << 5;
                uint4 vh, vl;
                if (i < 18) {
                    int co = k0 - 512 + skq;
                    vh = *(const uint4*)&ae2h[srr][co];
                    vl = *(const uint4*)&ae2l[srr][co];
                } else {
                    union U { uint4 q; u16 s[8]; } uh, ul;
                    uh.q = make_uint4(0, 0, 0, 0); ul.q = make_uint4(0, 0, 0, 0);
                    if (skq == 0) {
                        u16 hh = f2bf(tsq);
                        uh.s[0] = hh; ul.s[0] = f2bf(tsq - bf2f(hh));
                    }
                    vh = uh.q; vl = ul.q;
                }
                uint4 wh = *(const uint4*)(wph + k0);
                uint4 wl = *(const uint4*)(wpl + k0);
                __syncthreads();
                *(uint4*)&sh.A[0][0][srr][skq] = vh;
                *(uint4*)&sh.A[0][1][srr][skq] = vl;
                *(uint4*)&sh.Bw[0][0][srr][skq] = wh;
                *(uint4*)&sh.Bw[0][1][srr][skq] = wl;
                __syncthreads();
                bf16x8 ah = *(const bf16x8*)&sh.A[0][0][(ws << 4) + fr][ko];
                bf16x8 al = *(const bf16x8*)&sh.A[0][1][(ws << 4) + fr][ko];
                #pragma unroll
                for (int nt = 0; nt < 4; ++nt) {
                    bf16x8 bh = *(const bf16x8*)&sh.Bw[0][0][(nt << 4) + fr][ko];
                    bf16x8 bl = *(const bf16x8*)&sh.Bw[0][1][(nt << 4) + fr][ko];
                    acc[nt] = __builtin_amdgcn_mfma_f32_16x16x32_bf16(ah, bh, acc[nt], 0, 0, 0);
                    acc[nt] = __builtin_amdgcn_mfma_f32_16x16x32_bf16(ah, bl, acc[nt], 0, 0, 0);
                    acc[nt] = __builtin_amdgcn_mfma_f32_16x16x32_bf16(al, bh, acc[nt], 0, 0, 0);
                }
            }
        }
        // cell_t
        #pragma unroll
        for (int r = 0; r < 4; ++r) {
            int b = rbase + r;
            const float* bp = base_t + (size_t)b * G4 + (bx << 6) + fr;
            float gi = acc[0][r] + bp[0], gf = acc[1][r] + bp[16];
            float gg = acc[2][r] + bp[32], go = acc[3][r] + bp[48];
            float cn = sigm(gf) * ct_r[r] + sigm(gi) * tanhf(gg);
            ct_r[r] = cn;
            float h = sigm(go) * tanhf(cn);
            ast32(&xtn[(b << 9) + cell], packbf(h));
        }
        gsync_fast(bar, (++gen) * 32);
    }

    // ---- tail: ts head on final h_t (buffer 0, TT even) ----
    if (bx < 4) {
        float s[4];
        ts_strip(sh, Xt32 + (size_t)row0 * 512, W1h, b1, w2, bx, s);
        if (fr == 0) {
            #pragma unroll
            for (int r = 0; r < 4; ++r) astf(&tspart[(bx << 9) + rbase + r], s[r]);
        }
    }
    gsync_fast(bar, (++gen) * 32);
    if (bx == 0 && tid < 64) {
        int b = row0 + tid;
        out_ts[(b << 6) + 63] =
            aldf(&tspart[b]) + aldf(&tspart[512 + b]) +
            aldf(&tspart[1024 + b]) + aldf(&tspart[1536 + b]) + tsb2;
    }
}

// ---------------------------------------------------------------------------
// fp32 GEMM (latent section) — unchanged.
// ---------------------------------------------------------------------------
__device__ __forceinline__ int perm_src(int np) {
    int g = (np & 63) >> 4;
    int cell = ((np >> 6) << 4) + (np & 15);
    return (g << 9) + cell;
}

__global__ __launch_bounds__(256) void gemm_tn(
    const float* __restrict__ A, const float* __restrict__ Am,
    const float* __restrict__ Av, const float* __restrict__ Ae, int lda,
    const float* __restrict__ W1p, int ldw1,
    const float* __restrict__ W2p, int ldw2,
    int N, int K,
    const float* __restrict__ b1p, const float* __restrict__ b2p,
    float* __restrict__ C1, float* __restrict__ C2, int ldc,
    int relu, int permW)
{
    const float* W = W1p; int ldw = ldw1;
    const float* bias = b1p; float* C = C1;
    if (blockIdx.z == 1) { W = W2p; ldw = ldw2; bias = b2p; C = C2; }

    __shared__ __align__(16) float As[32][68];
    __shared__ __align__(16) float Ws[32][68];
    const int tid = threadIdx.x;
    const int tx = tid & 15, ty = tid >> 4;
    const int row0 = blockIdx.y << 6;
    const int col0 = blockIdx.x << 6;

    float acc[4][4] = {};

    for (int k0 = 0; k0 < K; k0 += 32) {
        #pragma unroll
        for (int s = 0; s < 2; ++s) {
            int f = tid + (s << 8);
            int rr = f >> 3;
            int kq = (f & 7) << 2;
            int k = k0 + kq;
            float4 v = make_float4(0.f, 0.f, 0.f, 0.f);
            size_t ro = (size_t)(row0 + rr) * (size_t)lda;
            if (Am) {
                if (k + 3 < K) {
                    float4 m = *(const float4*)(Am + ro + k);
                    float4 vv = *(const float4*)(Av + ro + k);
                    float4 e = *(const float4*)(Ae + ro + k);
                    v.x = fmaf(vv.x, e.x, m.x); v.y = fmaf(vv.y, e.y, m.y);
                    v.z = fmaf(vv.z, e.z, m.z); v.w = fmaf(vv.w, e.w, m.w);
                } else {
                    if (k + 0 < K) v.x = fmaf(Av[ro + k], Ae[ro + k], Am[ro + k]);
                    if (k + 1 < K) v.y = fmaf(Av[ro + k + 1], Ae[ro + k + 1], Am[ro + k + 1]);
                    if (k + 2 < K) v.z = fmaf(Av[ro + k + 2], Ae[ro + k + 2], Am[ro + k + 2]);
                }
            } else {
                const float* ap = A + ro;
                if (k + 3 < K) v = *(const float4*)(ap + k);
                else {
                    if (k + 0 < K) v.x = ap[k + 0];
                    if (k + 1 < K) v.y = ap[k + 1];
                    if (k + 2 < K) v.z = ap[k + 2];
                }
            }
            As[kq + 0][rr] = v.x; As[kq + 1][rr] = v.y;
            As[kq + 2][rr] = v.z; As[kq + 3][rr] = v.w;
        }
        #pragma unroll
        for (int s = 0; s < 2; ++s) {
            int f = tid + (s << 8);
            int rr = f >> 3;
            int kq = (f & 7) << 2;
            int k = k0 + kq;
            int n = col0 + rr;
            float4 v = make_float4(0.f, 0.f, 0.f, 0.f);
            if (n < N) {
                int nsrc = permW ? perm_src(n) : n;
                const float* wp = W + (size_t)nsrc * (size_t)ldw;
                if (k + 3 < K) v = *(const float4*)(wp + k);
                else {
                    if (k + 0 < K) v.x = wp[k + 0];
                    if (k + 1 < K) v.y = wp[k + 1];
                    if (k + 2 < K) v.z = wp[k + 2];
                }
            }
            Ws[kq + 0][rr] = v.x; Ws[kq + 1][rr] = v.y;
            Ws[kq + 2][rr] = v.z; Ws[kq + 3][rr] = v.w;
        }
        __syncthreads();
        #pragma unroll
        for (int k = 0; k < 32; ++k) {
            float4 av = *(const float4*)&As[k][ty << 2];
            float4 bv = *(const float4*)&Ws[k][tx << 2];
            acc[0][0] = fmaf(av.x, bv.x, acc[0][0]);
            acc[0][1] = fmaf(av.x, bv.y, acc[0][1]);
            acc[0][2] = fmaf(av.x, bv.z, acc[0][2]);
            acc[0][3] = fmaf(av.x, bv.w, acc[0][3]);
            acc[1][0] = fmaf(av.y, bv.x, acc[1][0]);
            acc[1][1] = fmaf(av.y, bv.y, acc[1][1]);
            acc[1][2] = fmaf(av.y, bv.z, acc[1][2]);
            acc[1][3] = fmaf(av.y, bv.w, acc[1][3]);
            acc[2][0] = fmaf(av.z, bv.x, acc[2][0]);
            acc[2][1] = fmaf(av.z, bv.y, acc[2][1]);
            acc[2][2] = fmaf(av.z, bv.z, acc[2][2]);
            acc[2][3] = fmaf(av.z, bv.w, acc[2][3]);
            acc[3][0] = fmaf(av.w, bv.x, acc[3][0]);
            acc[3][1] = fmaf(av.w, bv.y, acc[3][1]);
            acc[3][2] = fmaf(av.w, bv.z, acc[3][2]);
            acc[3][3] = fmaf(av.w, bv.w, acc[3][3]);
        }
        __syncthreads();
    }

    #pragma unroll
    for (int i = 0; i < 4; ++i) {
        int rr = row0 + (ty << 2) + i;
        float* cp = C + (size_t)rr * (size_t)ldc;
        #pragma unroll
        for (int j = 0; j < 4; ++j) {
            int cc = col0 + (tx << 2) + j;
            if (cc < N) {
                float v = acc[i][j];
                if (bias) v += bias[cc];
                if (relu) v = fmaxf(v, 0.f);
                cp[cc] = v;
            }
        }
    }
}

// ---------------------------------------------------------------------------
// One-shot packing — unchanged.
// ---------------------------------------------------------------------------
#define N_WE (G4 * 608)
#define N_WT (G4 * 608)
#define N_W1 (256 * 512)
#define N_E2 (64 * 512)
__global__ void pack_all(
    u16* __restrict__ Weh, u16* __restrict__ Wel,
    u16* __restrict__ Wth, u16* __restrict__ Wtl,
    u16* __restrict__ W1h,
    u16* __restrict__ E2h, u16* __restrict__ E2l,
    float* __restrict__ be, float* __restrict__ ba, float* __restrict__ bt,
    const float* __restrict__ eWih, const float* __restrict__ eWhh,
    const float* __restrict__ tWih, const float* __restrict__ tWhh,
    const float* __restrict__ ts1W, const float* __restrict__ e2W,
    const float* __restrict__ ebih, const float* __restrict__ ebhh,
    const float* __restrict__ abih, const float* __restrict__ abhh,
    const float* __restrict__ tbih, const float* __restrict__ tbhh)
{
    int idx = blockIdx.x * 256 + threadIdx.x;
    if (idx < N_WE) {
        int np = idx / 608, k = idx - np * 608;
        int n = perm_src(np);
        float v = 0.f;
        if (k < 65) v = eWih[n * 65 + k];
        else if (k < 577) v = eWhh[(n << 9) + k - 65];
        u16 h = f2bf(v); Weh[idx] = h; Wel[idx] = f2bf(v - bf2f(h));
        return;
    }
    idx -= N_WE;
    if (idx < N_WT) {
        int np = idx / 608, k = idx - np * 608;
        int n = perm_src(np);
        float v = 0.f;
        if (k < 512) v = tWhh[(n << 9) + k];
        else if (k < 576) v = tWih[n * 585 + 520 + (k - 512)];
        else if (k == 576) v = tWih[n * 585 + 584];
        u16 h = f2bf(v); Wth[idx] = h; Wtl[idx] = f2bf(v - bf2f(h));
        return;
    }
    idx -= N_WT;
    if (idx < N_W1) {
        W1h[idx] = f2bf(ts1W[idx]);
        return;
    }
    idx -= N_W1;
    if (idx < N_E2) {
        float v = e2W[idx];
        u16 h = f2bf(v); E2h[idx] = h; E2l[idx] = f2bf(v - bf2f(h));
        return;
    }
    idx -= N_E2;
    if (idx < G4) {
        int n = perm_src(idx);
        be[idx] = ebih[n] + ebhh[n];
        ba[idx] = abih[n] + abhh[n];
        bt[idx] = tbih[n] + tbhh[n];
    }
}

// ---------------------------------------------------------------------------
// init_all: interleaved X0 buffers, lens, attr->tcat, barrier counters.
// ---------------------------------------------------------------------------
__global__ __launch_bounds__(256) void init_all(
    u32* __restrict__ xe0, u32* __restrict__ xe1,
    int* __restrict__ lens, float* __restrict__ tcat,
    u32* __restrict__ xa0, u32* __restrict__ xt0,
    const int* __restrict__ acts, const float* __restrict__ tsv,
    const float* __restrict__ act_emb,
    const int* __restrict__ attr_cat, const float* __restrict__ attr_num,
    const float* __restrict__ attr_emb,
    const float* __restrict__ a2aW, const float* __restrict__ a2ab,
    int* __restrict__ bars)
{
    int b = blockIdx.x, tid = threadIdx.x;
    if (b == 0) {
        for (int j = tid; j < 1024; j += 256)
            __hip_atomic_store(&bars[j], 0, __ATOMIC_RELAXED, __HIP_MEMORY_SCOPE_AGENT);
    }
    for (int j = tid; j < 608; j += 256) {
        float v = 0.f;
        if (j < 64) v = act_emb[acts[b << 6] * 64 + j];
        else if (j == 64) v = tsv[b << 6];
        xe0[b * 608 + j] = packbf(v);
        if (j >= 577) xe1[b * 608 + j] = 0;
    }
    for (int j = tid; j < CF; j += 256) {
        xt0[(b << 9) + j] = 0;
    }
    for (int j = tid; j < 576; j += 256) {
        float v = (j < 64) ? act_emb[63 * 64 + j] : 0.f;
        xa0[b * 576 + j] = packbf(v);
    }
    if (tid < 64) {
        int v = acts[(b << 6) + tid];
        int m = v;
        #pragma unroll
        for (int off = 32; off; off >>= 1) m = max(m, __shfl_xor(m, off));
        unsigned long long mask = __ballot(v == m);
        if (tid == 0) lens[b] = __ffsll(mask) - 1;
    }
    if (tid < 8) {
        const float* wr = a2aW + tid * 17;
        const float* em = attr_emb + attr_cat[b] * 16;
        float s = a2ab[tid];
        #pragma unroll
        for (int k = 0; k < 16; ++k) s = fmaf(em[k], wr[k], s);
        s = fmaf(attr_num[b], wr[16], s);
        tcat[b * TDIM + tid] = fmaxf(s, 0.f);
    }
}

__global__ __launch_bounds__(64) void attr_heads(
    const float* __restrict__ hid1, const float* __restrict__ hid2,
    const float* __restrict__ tc2W, const float* __restrict__ tc2b,
    const float* __restrict__ tn2W, const float* __restrict__ tn2b,
    float* __restrict__ out_cat, float* __restrict__ out_num) {
    __shared__ __align__(16) float h1[260], h2[260], sl[10];
    int b = blockIdx.x, tid = threadIdx.x;
    for (int k = tid; k < 260; k += 64) {
        h1[k] = hid1[b * 260 + k];
        h2[k] = hid2[b * 260 + k];
    }
    __syncthreads();
    if (tid < 10) {
        float l = tc2b[tid];
        const float* wr = tc2W + tid * 260;
        for (int k = 0; k < 260; ++k) l = fmaf(h1[k], wr[k], l);
        sl[tid] = l;
    }
    __syncthreads();
    if (tid < 10) {
        float m = sl[0];
        for (int i = 1; i < 10; ++i) m = fmaxf(m, sl[i]);
        float ssum = 0.f;
        for (int i = 0; i < 10; ++i) ssum += expf(sl[i] - m);
        out_cat[b * 10 + tid] = expf(sl[tid] - m) / ssum;
    }
    float p = 0.f;
    for (int k = tid; k < 260; k += 64) p = fmaf(h2[k], tn2W[k], p);
    #pragma unroll
    for (int off = 32; off; off >>= 1) p += __shfl_xor(p, off);
    if (tid == 0) out_num[b] = 1.f / (1.f + expf(-(p + tn2b[0])));
}

// ---------------------------------------------------------------------------
extern "C" void kernel_launch(void* const* d_in, const int* in_sizes, int n_in,
                              void* d_out, int out_size, void* d_ws, size_t ws_size,
                              hipStream_t stream) {
    const int*   attr_cat = (const int*)  d_in[0];
    const float* attr_num = (const float*)d_in[1];
    const int*   acts     = (const int*)  d_in[2];
    const float* tsv      = (const float*)d_in[3];
    const float* eps      = (const float*)d_in[4];
    const float* attr_emb = (const float*)d_in[5];
    const float* a2a_W    = (const float*)d_in[6];
    const float* a2a_b    = (const float*)d_in[7];
    const float* act_emb  = (const float*)d_in[8];
    const float* eWih     = (const float*)d_in[9];
    const float* eWhh     = (const float*)d_in[10];
    const float* ebih     = (const float*)d_in[11];
    const float* ebhh     = (const float*)d_in[12];
    const float* mean_W   = (const float*)d_in[13];
    const float* mean_b   = (const float*)d_in[14];
    const float* var_W    = (const float*)d_in[15];
    const float* var_b    = (const float*)d_in[16];
    const float* z2t_W    = (const float*)d_in[17];
    const float* z2t_b    = (const float*)d_in[18];
    const float* tc1_W    = (const float*)d_in[19];
    const float* tc1_b    = (const float*)d_in[20];
    const float* tc2_W    = (const float*)d_in[21];
    const float* tc2_b    = (const float*)d_in[22];
    const float* tn1_W    = (const float*)d_in[23];
    const float* tn1_b    = (const float*)d_in[24];
    const float* tn2_W    = (const float*)d_in[25];
    const float* tn2_b    = (const float*)d_in[26];
    const float* aWih     = (const float*)d_in[27];
    const float* aWhh     = (const float*)d_in[28];
    const float* abih     = (const float*)d_in[29];
    const float* abhh     = (const float*)d_in[30];
    const float* tWih     = (const float*)d_in[31];
    const float* tWhh     = (const float*)d_in[32];
    const float* tbih     = (const float*)d_in[33];
    const float* tbhh     = (const float*)d_in[34];
    const float* e2act_W  = (const float*)d_in[35];
    const float* e2act_b  = (const float*)d_in[36];
    const float* ts1_W    = (const float*)d_in[37];
    const float* ts1_b    = (const float*)d_in[38];
    const float* ts2_W    = (const float*)d_in[39];
    const float* ts2_b    = (const float*)d_in[40];

    float* out = (float*)d_out;
    float* out_cat  = out;
    float* out_num  = out + 5120;
    float* out_acts = out + 5632;
    float* out_ts   = out + 2102784;
    float* outm     = out + 2135552;
    float* outv     = out + 2201088;

    char* w = (char*)d_ws;
    auto alloc = [&](size_t bytes) { char* p = w; w += (bytes + 255) & ~(size_t)255; return p; };
    // --- persistent region ---
    u16*   Wt_hi  = (u16*)alloc((size_t)G4 * 608 * 2);
    u16*   Wt_lo  = (u16*)alloc((size_t)G4 * 608 * 2);
    u16*   W1h    = (u16*)alloc(256 * 512 * 2);
    u16*   E2h    = (u16*)alloc(64 * 512 * 2);
    u16*   E2l    = (u16*)alloc(64 * 512 * 2);
    float* bias_e = (float*)alloc(G4 * 4);
    float* bias_a = (float*)alloc(G4 * 4);
    float* bias_t = (float*)alloc(G4 * 4);
    float* base_a = (float*)alloc((size_t)B * G4 * 4);
    float* base_t = (float*)alloc((size_t)B * G4 * 4);
    u32*   Xa32   = (u32*)alloc((size_t)2 * B * 576 * 4);
    u32*   Xt32   = (u32*)alloc((size_t)2 * B * 512 * 4);
    float* tcat   = (float*)alloc((size_t)B * TDIM * 4);
    float* t_rec  = (float*)alloc((size_t)B * TDIM * 4);
    float* hid1   = (float*)alloc((size_t)B * 260 * 4);
    float* hid2   = (float*)alloc((size_t)B * 260 * 4);
    int*   lens   = (int*)alloc(512 * 4);
    float* partial4 = (float*)alloc(4 * 512 * 4);
    int*   bars   = (int*)alloc(4096);  // [by*32]=enc, [256+by*32]=dec, [512]=global
    // --- phase overlay: encoder {We,Xe} / decoder {Wa} ---
    char* phase = w;
    u16*   We_hi  = (u16*)(phase);
    u16*   We_lo  = (u16*)(phase + (size_t)G4 * 608 * 2);
    u32*   Xe32   = (u32*)(phase + (size_t)2 * G4 * 608 * 2);
    u16*   Wa_hi  = (u16*)(phase);
    u16*   Wa_lo  = (u16*)(phase + (size_t)G4 * 576 * 2);
    (void)ws_size; (void)in_sizes; (void)n_in; (void)out_size;

    // ---- prep (2 launches) ----
    {
        int total = N_WE + N_WT + N_W1 + N_E2 + G4;
        pack_all<<<(total + 255) / 256, 256, 0, stream>>>(
            We_hi, We_lo, Wt_hi, Wt_lo, W1h, E2h, E2l,
            bias_e, bias_a, bias_t,
            eWih, eWhh, tWih, tWhh, ts1_W, e2act_W,
            ebih, ebhh, abih, abhh, tbih, tbhh);
    }
    init_all<<<B, 256, 0, stream>>>(
        Xe32, Xe32 + (size_t)B * 608,
        lens, tcat, Xa32, Xt32,
        acts, tsv, act_emb, attr_cat, attr_num, attr_emb, a2a_W, a2a_b,
        bars);

    // ---- encoder (1 persistent launch, 63 per-by barriers) ----
    enc_coop<<<dim3(32, 8), 256, 0, stream>>>(
        Xe32, We_hi, We_lo, bias_e, tcat, lens, acts, tsv, act_emb,
        bars);

    // ---- latent (5 launches) ----
    gemm_tn<<<dim3(2, 8, 2), 256, 0, stream>>>(
        tcat, nullptr, nullptr, nullptr, TDIM, mean_W, TDIM, var_W, TDIM,
        ZD, TDIM, mean_b, var_b, outm, outv, ZD, 0, 0);
    gemm_tn<<<dim3(9, 8, 1), 256, 0, stream>>>(
        nullptr, outm, outv, eps, ZD, z2t_W, ZD, nullptr, 0,
        TDIM, ZD, z2t_b, nullptr, t_rec, nullptr, TDIM, 1, 0);
    gemm_tn<<<dim3(5, 8, 2), 256, 0, stream>>>(
        t_rec, nullptr, nullptr, nullptr, TDIM, tc1_W, TDIM, tn1_W, TDIM,
        260, TDIM, tc1_b, tn1_b, hid1, hid2, 260, 1, 0);
    attr_heads<<<B, 64, 0, stream>>>(hid1, hid2, tc2_W, tc2_b, tn2_W, tn2_b, out_cat, out_num);
    gemm_tn<<<dim3(32, 8, 2), 256, 0, stream>>>(
        t_rec, nullptr, nullptr, nullptr, TDIM, aWih, 584, tWih, 585,
        G4, TDIM, bias_a, bias_t, base_a, base_t, G4, 0, 1);

    // ---- decoder (1 persistent launch) ----
    dec_coop<<<dim3(32, 8), 256, 0, stream>>>(
        Xa32, Wa_hi, Wa_lo, aWih, aWhh, base_a,
        Xt32, Wt_hi, Wt_lo, base_t,
        E2h, E2l, e2act_b, act_emb, out_acts, out_ts,
        W1h, ts1_b, ts2_W, ts2_b, partial4,
        bars);
}